// Round 9
// baseline (737.135 us; speedup 1.0000x reference)
//
#include <hip/hip_runtime.h>
#include <hip/hip_cooperative_groups.h>
#include <stdint.h>

namespace cg = cooperative_groups;

#define NFEAT 4096
#define GRID 1024
#define BLK 256              /* 4 waves/block, 4 blocks/CU co-resident */
#define WPB (BLK / 64)       /* waves per block = 4 */
#define RPW 2                /* rows per wave; GRID*WPB*RPW = 8192 */

// fallback-path constants
#define NSLOT 64
#define SLOT_STRIDE 16

// ---------------------------------------------------------------------------
// Exact emulation of the reference's LUT-based rounded integer sqrt.
// ---------------------------------------------------------------------------
__device__ __forceinline__ int isqrt_floor_small(int v) {
    int m = (int)sqrtf((float)v);
    m -= (m * m > v);
    m += ((m + 1) * (m + 1) <= v);
    return m;
}

__device__ __forceinline__ int sqrt_rounded_ref(int d) {
    if (d <= 0) return 0;
    int msb = 31 - __clz(d);
    int k = msb >> 1;
    int sh = (7 - k) * 2;
    int dn = d << sh;
    int la = (dn >> 8) & 255;
    int mant = isqrt_floor_small(la * 256 + 128);
    int qf = mant >> (7 - k);
    int bnd = qf * qf + qf;
    return (d > bnd) ? (qf + 1) : qf;
}

// Correctly-rounded x/s for uniform divisor s, rs = RN(1/s). Markstein fixup.
__device__ __forceinline__ float div_rn(float x, float s, float rs) {
    float q0 = x * rs;
    float r  = fmaf(-s, q0, x);
    return fmaf(r, rs, q0);
}

// Max over GRID plain uint slots; every lane returns the global max as float.
__device__ __forceinline__ float slots_max(const unsigned* __restrict__ s, int lane) {
    unsigned v = 0;
#pragma unroll
    for (int i = 0; i < GRID / 64; ++i) {
        unsigned a = s[lane + i * 64];
        v = v > a ? v : a;
    }
#pragma unroll
    for (int off = 32; off; off >>= 1) {
        unsigned o = (unsigned)__shfl_xor((int)v, off);
        v = v > o ? v : o;
    }
    return __uint_as_float(v);
}

// ---------------------------------------------------------------------------
// Phase-2 worker: quantize one row, exact int sums -> mu/inv (all lanes),
// y-absmax folded into ym. pk[] lives only inside this call (16 VGPRs, reused).
// ---------------------------------------------------------------------------
__device__ __forceinline__ void p2_row(const float4* __restrict__ xr4,
                                       const float4* __restrict__ g4,
                                       const float4* __restrict__ b4,
                                       int lane, float s, float rs,
                                       float& mu_out, float& inv_out, float& ym) {
    uint32_t pk[16];
    int s1 = 0, s2 = 0;
#pragma unroll
    for (int c = 0; c < 16; ++c) {
        float4 v = xr4[c * 64 + lane];
        float q0 = rintf(div_rn(v.x, s, rs));
        float q1 = rintf(div_rn(v.y, s, rs));
        float q2 = rintf(div_rn(v.z, s, rs));
        float q3 = rintf(div_rn(v.w, s, rs));
        q0 = fminf(fmaxf(q0, -127.0f), 127.0f);
        q1 = fminf(fmaxf(q1, -127.0f), 127.0f);
        q2 = fminf(fmaxf(q2, -127.0f), 127.0f);
        q3 = fminf(fmaxf(q3, -127.0f), 127.0f);
        int i0 = (int)q0, i1 = (int)q1, i2 = (int)q2, i3 = (int)q3;
        pk[c] = (uint32_t)(i0 & 255) | ((uint32_t)(i1 & 255) << 8) |
                ((uint32_t)(i2 & 255) << 16) | ((uint32_t)i3 << 24);
        s1 += i0 + i1 + i2 + i3;
        s2 += i0 * i0 + i1 * i1 + i2 * i2 + i3 * i3;
    }
#pragma unroll
    for (int off = 32; off; off >>= 1) {
        s1 += __shfl_xor(s1, off);
        s2 += __shfl_xor(s2, off);
    }
    float Ex  = (float)s1 * s;
    float Ex2 = (float)s2 * s * s;
    float mu  = Ex / (float)NFEAT;
    float var = fmaxf(Ex2 / (float)NFEAT - mu * mu, 0.0f);
    float vr  = fminf(fmaxf(rintf(var), 1.0f), 65535.0f);
    int sdi   = sqrt_rounded_ref((int)vr);
    float inv = 1.0f / fmaxf((float)sdi, 1e-5f);
#pragma unroll
    for (int c = 0; c < 16; ++c) {
        uint32_t p = pk[c];
        float4 gm = g4[c * 64 + lane];
        float4 bt = b4[c * 64 + lane];
        int i0 = (int)(int8_t)(p & 255);
        int i1 = (int)(int8_t)((p >> 8) & 255);
        int i2 = (int)(int8_t)((p >> 16) & 255);
        int i3 = (int)(int8_t)((p >> 24) & 255);
        float y0 = ((float)i0 * s - mu) * inv * gm.x + bt.x;
        float y1 = ((float)i1 * s - mu) * inv * gm.y + bt.y;
        float y2 = ((float)i2 * s - mu) * inv * gm.z + bt.z;
        float y3 = ((float)i3 * s - mu) * inv * gm.w + bt.w;
        ym = fmaxf(ym, fmaxf(fmaxf(fabsf(y0), fabsf(y1)),
                             fmaxf(fabsf(y2), fabsf(y3))));
    }
    mu_out = mu;
    inv_out = inv;
}

// ---------------------------------------------------------------------------
// Phase-3 worker: re-read row (L3-hot), requantize bit-identically, write.
// ---------------------------------------------------------------------------
__device__ __forceinline__ void p3_row(const float4* __restrict__ xr4,
                                       const float4* __restrict__ g4,
                                       const float4* __restrict__ b4,
                                       float4* __restrict__ o4,
                                       int lane, float s, float rs,
                                       float mu, float inv, float so, float rso) {
#pragma unroll
    for (int c = 0; c < 16; ++c) {
        float4 v = xr4[c * 64 + lane];
        float4 gm = g4[c * 64 + lane];
        float4 bt = b4[c * 64 + lane];
        float q0 = rintf(div_rn(v.x, s, rs));
        float q1 = rintf(div_rn(v.y, s, rs));
        float q2 = rintf(div_rn(v.z, s, rs));
        float q3 = rintf(div_rn(v.w, s, rs));
        q0 = fminf(fmaxf(q0, -127.0f), 127.0f);
        q1 = fminf(fmaxf(q1, -127.0f), 127.0f);
        q2 = fminf(fmaxf(q2, -127.0f), 127.0f);
        q3 = fminf(fmaxf(q3, -127.0f), 127.0f);
        float y0 = (q0 * s - mu) * inv * gm.x + bt.x;   // q integral == (float)(int)q
        float y1 = (q1 * s - mu) * inv * gm.y + bt.y;
        float y2 = (q2 * s - mu) * inv * gm.z + bt.z;
        float y3 = (q3 * s - mu) * inv * gm.w + bt.w;
        float o0 = fminf(fmaxf(rintf(div_rn(y0, so, rso)), -127.0f), 127.0f) * so;
        float o1 = fminf(fmaxf(rintf(div_rn(y1, so, rso)), -127.0f), 127.0f) * so;
        float o2 = fminf(fmaxf(rintf(div_rn(y2, so, rso)), -127.0f), 127.0f) * so;
        float o3 = fminf(fmaxf(rintf(div_rn(y3, so, rso)), -127.0f), 127.0f) * so;
        o4[c * 64 + lane] = make_float4(o0, o1, o2, o3);
    }
}

// ===========================================================================
// Cooperative fused kernel. Wave gw owns rows 2gw, 2gw+1 in ALL phases.
// Only 6 scalars (s, rs, muA, invA, muB, invB) live across grid syncs.
// ===========================================================================
__global__ __launch_bounds__(BLK, 4) void fused_kernel(
    const float* __restrict__ x, const float* __restrict__ gamma,
    const float* __restrict__ beta, float* __restrict__ out,
    unsigned* __restrict__ slot, unsigned* __restrict__ slot2, int rows) {
#pragma clang fp contract(off)
    cg::grid_group gridg = cg::this_grid();
    const int bid = blockIdx.x;
    const int t = threadIdx.x;
    const int lane = t & 63;
    const int wave = t >> 6;
    const float4* g4 = (const float4*)gamma;
    const float4* b4 = (const float4*)beta;

    __shared__ float redf[WPB];

    const int gw = bid * WPB + wave;
    const float4* xA = (const float4*)(x + (size_t)gw * RPW * NFEAT);
    const float4* xB = xA + NFEAT / 4;
    float4* oA = (float4*)(out + (size_t)gw * RPW * NFEAT);
    float4* oB = oA + NFEAT / 4;

    // ---------------- phase 1: absmax over this wave's own 2 rows ----------
    {
        float m = 0.0f;
#pragma unroll
        for (int c = 0; c < 16; ++c) {
            float4 a = xA[c * 64 + lane];
            float4 b = xB[c * 64 + lane];
            float ma = fmaxf(fmaxf(fabsf(a.x), fabsf(a.y)), fmaxf(fabsf(a.z), fabsf(a.w)));
            float mb = fmaxf(fmaxf(fabsf(b.x), fabsf(b.y)), fmaxf(fabsf(b.z), fabsf(b.w)));
            m = fmaxf(m, fmaxf(ma, mb));
        }
#pragma unroll
        for (int off = 32; off; off >>= 1) m = fmaxf(m, __shfl_down(m, off));
        if (lane == 0) redf[wave] = m;
        __syncthreads();
        if (t == 0) {
            float mm = redf[0];
#pragma unroll
            for (int i2 = 1; i2 < WPB; ++i2) mm = fmaxf(mm, redf[i2]);
            slot[bid] = __float_as_uint(mm);
        }
        __syncthreads();   // redf reused for ymax
    }
    gridg.sync();

    // ---------------- phase 2: per-row stats + y absmax, wave-local --------
    const float s  = fmaxf(slots_max(slot, lane) / 127.0f, 1e-8f);
    const float rs = 1.0f / s;
    float muA, invA, muB, invB;
    float ym = 0.0f;
    p2_row(xA, g4, b4, lane, s, rs, muA, invA, ym);
    p2_row(xB, g4, b4, lane, s, rs, muB, invB, ym);
#pragma unroll
    for (int off = 32; off; off >>= 1) ym = fmaxf(ym, __shfl_down(ym, off));
    if (lane == 0) redf[wave] = ym;
    __syncthreads();
    if (t == 0) {
        float mm = redf[0];
#pragma unroll
        for (int i2 = 1; i2 < WPB; ++i2) mm = fmaxf(mm, redf[i2]);
        slot2[bid] = __float_as_uint(mm);
    }
    gridg.sync();

    // ---------------- phase 3: requantize + write --------------------------
    const float so  = fmaxf(slots_max(slot2, lane) / 127.0f, 1e-8f);
    const float rso = 1.0f / so;
    p3_row(xA, g4, b4, oA, lane, s, rs, muA, invA, so, rso);
    p3_row(xB, g4, b4, oB, lane, s, rs, muB, invB, so, rso);
}

// ===========================================================================
// Fallback path (proven R5 kernels).
// ===========================================================================
__device__ __forceinline__ float slot_max64(const unsigned* __restrict__ slots) {
    unsigned v = slots[(threadIdx.x & 63) * SLOT_STRIDE];
#pragma unroll
    for (int off = 32; off; off >>= 1) {
        unsigned o = (unsigned)__shfl_xor((int)v, off);
        v = v > o ? v : o;
    }
    return __uint_as_float(v);
}

__global__ __launch_bounds__(256, 4) void absmax_kernel(const float* __restrict__ x,
                                                        int n4,
                                                        unsigned* __restrict__ hx) {
    const float4* x4 = (const float4*)x;
    int i = blockIdx.x * 256 + threadIdx.x;
    const int stride = gridDim.x * 256;
    float m = 0.0f;
    for (; i + 3 * stride < n4; i += 4 * stride) {
        float4 a = x4[i];
        float4 b = x4[i + stride];
        float4 c = x4[i + 2 * stride];
        float4 d = x4[i + 3 * stride];
        float ma = fmaxf(fmaxf(fabsf(a.x), fabsf(a.y)), fmaxf(fabsf(a.z), fabsf(a.w)));
        float mb = fmaxf(fmaxf(fabsf(b.x), fabsf(b.y)), fmaxf(fabsf(b.z), fabsf(b.w)));
        float mc = fmaxf(fmaxf(fabsf(c.x), fabsf(c.y)), fmaxf(fabsf(c.z), fabsf(c.w)));
        float md = fmaxf(fmaxf(fabsf(d.x), fabsf(d.y)), fmaxf(fabsf(d.z), fabsf(d.w)));
        m = fmaxf(m, fmaxf(fmaxf(ma, mb), fmaxf(mc, md)));
    }
    for (; i < n4; i += stride) {
        float4 a = x4[i];
        m = fmaxf(m, fmaxf(fmaxf(fabsf(a.x), fabsf(a.y)), fmaxf(fabsf(a.z), fabsf(a.w))));
    }
#pragma unroll
    for (int off = 32; off; off >>= 1) m = fmaxf(m, __shfl_down(m, off));
    __shared__ float smax[4];
    int lane = threadIdx.x & 63, w = threadIdx.x >> 6;
    if (lane == 0) smax[w] = m;
    __syncthreads();
    if (threadIdx.x == 0) {
        m = fmaxf(fmaxf(smax[0], smax[1]), fmaxf(smax[2], smax[3]));
        atomicMax(hx + (blockIdx.x & (NSLOT - 1)) * SLOT_STRIDE, __float_as_uint(m));
    }
}

__global__ __launch_bounds__(256, 4) void rowstat_kernel(
    const float* __restrict__ x, const float* __restrict__ gamma,
    const float* __restrict__ beta, const unsigned* __restrict__ hx,
    unsigned* __restrict__ hy,
    float* __restrict__ row_mu, float* __restrict__ row_inv) {
#pragma clang fp contract(off)
    const int row = blockIdx.x;
    const int t = threadIdx.x;
    const float4* xr = (const float4*)(x + (size_t)row * NFEAT);
    float4 v0 = xr[t];
    float4 v1 = xr[256 + t];
    float4 v2 = xr[512 + t];
    float4 v3 = xr[768 + t];
    const float s  = fmaxf(slot_max64(hx) / 127.0f, 1e-8f);
    const float rs = 1.0f / s;

    float xv[16] = {v0.x, v0.y, v0.z, v0.w, v1.x, v1.y, v1.z, v1.w,
                    v2.x, v2.y, v2.z, v2.w, v3.x, v3.y, v3.z, v3.w};
    int xi[16];
    int s1 = 0, s2 = 0;
#pragma unroll
    for (int k = 0; k < 16; ++k) {
        float q = rintf(div_rn(xv[k], s, rs));
        q = fminf(fmaxf(q, -127.0f), 127.0f);
        int qi = (int)q;
        xi[k] = qi;
        s1 += qi;
        s2 += qi * qi;
    }
#pragma unroll
    for (int off = 32; off; off >>= 1) {
        s1 += __shfl_down(s1, off);
        s2 += __shfl_down(s2, off);
    }
    __shared__ int a1[4], a2[4];
    __shared__ float smu1, sinv1;
    const int lane = t & 63, w = t >> 6;
    if (lane == 0) { a1[w] = s1; a2[w] = s2; }
    __syncthreads();
    if (t == 0) {
        int Exi = a1[0] + a1[1] + a1[2] + a1[3];
        int Ex2i = a2[0] + a2[1] + a2[2] + a2[3];
        float Ex = (float)Exi * s;
        float Ex2 = (float)Ex2i * s * s;
        float mu = Ex / (float)NFEAT;
        float var = fmaxf(Ex2 / (float)NFEAT - mu * mu, 0.0f);
        float vr = fminf(fmaxf(rintf(var), 1.0f), 65535.0f);
        int std_int = sqrt_rounded_ref((int)vr);
        float inv_std = 1.0f / fmaxf((float)std_int, 1e-5f);
        row_mu[row] = mu;
        row_inv[row] = inv_std;
        smu1 = mu;
        sinv1 = inv_std;
    }
    __syncthreads();
    const float mu = smu1, inv = sinv1;
    float ym = 0.0f;
#pragma unroll
    for (int g = 0; g < 4; ++g) {
        float4 gm = ((const float4*)gamma)[g * 256 + t];
        float4 bt = ((const float4*)beta)[g * 256 + t];
        float gv[4] = {gm.x, gm.y, gm.z, gm.w};
        float bv[4] = {bt.x, bt.y, bt.z, bt.w};
#pragma unroll
        for (int j = 0; j < 4; ++j) {
            float xq = (float)xi[g * 4 + j] * s;
            float xn = (xq - mu) * inv;
            float y = xn * gv[j] + bv[j];
            ym = fmaxf(ym, fabsf(y));
        }
    }
#pragma unroll
    for (int off = 32; off; off >>= 1) ym = fmaxf(ym, __shfl_down(ym, off));
    __shared__ float aym[4];
    if (lane == 0) aym[w] = ym;
    __syncthreads();
    if (t == 0) {
        float m = fmaxf(fmaxf(aym[0], aym[1]), fmaxf(aym[2], aym[3]));
        atomicMax(hy + (row & (NSLOT - 1)) * SLOT_STRIDE, __float_as_uint(m));
    }
}

__global__ __launch_bounds__(256, 4) void quantout_f_kernel(
    const float* __restrict__ x, const float* __restrict__ gamma,
    const float* __restrict__ beta, const unsigned* __restrict__ hx,
    const unsigned* __restrict__ hy,
    const float* __restrict__ row_mu, const float* __restrict__ row_inv,
    float* __restrict__ out) {
#pragma clang fp contract(off)
    const int row = blockIdx.x;
    const int t = threadIdx.x;
    const float4* xr = (const float4*)(x + (size_t)row * NFEAT);
    float4 w0 = xr[t];
    float4 w1 = xr[256 + t];
    float4 w2 = xr[512 + t];
    float4 w3 = xr[768 + t];
    const float s_in  = fmaxf(slot_max64(hx) / 127.0f, 1e-8f);
    const float s_out = fmaxf(slot_max64(hy) / 127.0f, 1e-8f);
    const float rsi = 1.0f / s_in;
    const float rso = 1.0f / s_out;
    const float mu = row_mu[row], inv = row_inv[row];
    float4 vv[4] = {w0, w1, w2, w3};
    float4* outr = (float4*)(out + (size_t)row * NFEAT);
#pragma unroll
    for (int g = 0; g < 4; ++g) {
        float4 v = vv[g];
        float4 gm = ((const float4*)gamma)[g * 256 + t];
        float4 bt = ((const float4*)beta)[g * 256 + t];
        float xv[4] = {v.x, v.y, v.z, v.w};
        float gv[4] = {gm.x, gm.y, gm.z, gm.w};
        float bv[4] = {bt.x, bt.y, bt.z, bt.w};
        float o[4];
#pragma unroll
        for (int j = 0; j < 4; ++j) {
            float q = rintf(div_rn(xv[j], s_in, rsi));
            q = fminf(fmaxf(q, -127.0f), 127.0f);
            float xq = q * s_in;
            float xn = (xq - mu) * inv;
            float y = xn * gv[j] + bv[j];
            float qq = rintf(div_rn(y, s_out, rso));
            qq = fminf(fmaxf(qq, -127.0f), 127.0f);
            o[j] = qq * s_out;
        }
        outr[g * 256 + t] = make_float4(o[0], o[1], o[2], o[3]);
    }
}

extern "C" void kernel_launch(void* const* d_in, const int* in_sizes, int n_in,
                              void* d_out, int out_size, void* d_ws, size_t ws_size,
                              hipStream_t stream) {
    const float* x = (const float*)d_in[0];
    const float* gamma = (const float*)d_in[1];
    const float* beta = (const float*)d_in[2];
    float* out = (float*)d_out;

    const int total = in_sizes[0];
    int rows = total / NFEAT;

    char* ws = (char*)d_ws;
    unsigned* slot  = (unsigned*)ws;               // GRID * 4 B
    unsigned* slot2 = (unsigned*)(ws + 4096);      // GRID * 4 B

    if (rows == GRID * WPB * RPW) {
        void* args[] = {(void*)&x, (void*)&gamma, (void*)&beta, (void*)&out,
                        (void*)&slot, (void*)&slot2, (void*)&rows};
        hipError_t e = hipLaunchCooperativeKernel((void*)fused_kernel,
                                                  dim3(GRID), dim3(BLK),
                                                  args, 0, stream);
        if (e == hipSuccess) return;
    }

    // ---------------- fallback: proven 3-kernel path ----------------
    unsigned* hx = (unsigned*)ws;
    unsigned* hy = (unsigned*)(ws + 4096);
    float* row_mu = (float*)(ws + 8192);
    float* row_inv = row_mu + rows;

    hipMemsetAsync(ws, 0, 8192, stream);
    absmax_kernel<<<2048, 256, 0, stream>>>(x, total / 4, hx);
    rowstat_kernel<<<rows, 256, 0, stream>>>(x, gamma, beta, hx, hy,
                                             row_mu, row_inv);
    quantout_f_kernel<<<rows, 256, 0, stream>>>(x, gamma, beta, hx, hy,
                                                row_mu, row_inv, out);
}

// Round 14
// 295.270 us; speedup vs baseline: 2.4965x; 2.4965x over previous
//
#include <hip/hip_runtime.h>
#include <stdint.h>

#define NFEAT 4096
#define ABS_GRID 2048        /* absmax blocks == hx slot count */

// ---------------------------------------------------------------------------
// Exact emulation of the reference's LUT-based rounded integer sqrt.
// ---------------------------------------------------------------------------
__device__ __forceinline__ int isqrt_floor_small(int v) {
    int m = (int)sqrtf((float)v);
    m -= (m * m > v);
    m += ((m + 1) * (m + 1) <= v);
    return m;
}

__device__ __forceinline__ int sqrt_rounded_ref(int d) {
    if (d <= 0) return 0;
    int msb = 31 - __clz(d);
    int k = msb >> 1;
    int sh = (7 - k) * 2;
    int dn = d << sh;
    int la = (dn >> 8) & 255;
    int mant = isqrt_floor_small(la * 256 + 128);
    int qf = mant >> (7 - k);
    int bnd = qf * qf + qf;
    return (d > bnd) ? (qf + 1) : qf;
}

// Correctly-rounded x/s for uniform divisor s, rs = RN(1/s). Markstein fixup.
__device__ __forceinline__ float div_rn(float x, float s, float rs) {
    float q0 = x * rs;
    float r  = fmaf(-s, q0, x);
    return fmaf(r, rs, q0);
}

// Max over n plain uint slots (abs-float bits: uint cmp == float cmp).
// All 64 lanes of the calling wave return the max.
__device__ __forceinline__ unsigned slots_max_u(const unsigned* __restrict__ s,
                                                int n, int lane) {
    unsigned v = 0;
    for (int i = lane; i < n; i += 64) {
        unsigned a = s[i];
        v = v > a ? v : a;
    }
#pragma unroll
    for (int off = 32; off; off >>= 1) {
        unsigned o = (unsigned)__shfl_xor((int)v, off);
        v = v > o ? v : o;
    }
    return v;
}

// ===========================================================================
// K1: global absmax of x. Plain store hx[bid] — no atomics, no memset needed.
// ===========================================================================
__global__ __launch_bounds__(256, 4) void absmax_ps(const float* __restrict__ x,
                                                    int n4,
                                                    unsigned* __restrict__ hx) {
    const float4* x4 = (const float4*)x;
    int i = blockIdx.x * 256 + threadIdx.x;
    const int stride = ABS_GRID * 256;
    float m = 0.0f;
    for (; i + 3 * stride < n4; i += 4 * stride) {
        float4 a = x4[i];
        float4 b = x4[i + stride];
        float4 c = x4[i + 2 * stride];
        float4 d = x4[i + 3 * stride];
        float ma = fmaxf(fmaxf(fabsf(a.x), fabsf(a.y)), fmaxf(fabsf(a.z), fabsf(a.w)));
        float mb = fmaxf(fmaxf(fabsf(b.x), fabsf(b.y)), fmaxf(fabsf(b.z), fabsf(b.w)));
        float mc = fmaxf(fmaxf(fabsf(c.x), fabsf(c.y)), fmaxf(fabsf(c.z), fabsf(c.w)));
        float md = fmaxf(fmaxf(fabsf(d.x), fabsf(d.y)), fmaxf(fabsf(d.z), fabsf(d.w)));
        m = fmaxf(m, fmaxf(fmaxf(ma, mb), fmaxf(mc, md)));
    }
    for (; i < n4; i += stride) {
        float4 a = x4[i];
        m = fmaxf(m, fmaxf(fmaxf(fabsf(a.x), fabsf(a.y)), fmaxf(fabsf(a.z), fabsf(a.w))));
    }
#pragma unroll
    for (int off = 32; off; off >>= 1) m = fmaxf(m, __shfl_down(m, off));
    __shared__ float smax[4];
    int lane = threadIdx.x & 63, w = threadIdx.x >> 6;
    if (lane == 0) smax[w] = m;
    __syncthreads();
    if (threadIdx.x == 0) {
        m = fmaxf(fmaxf(smax[0], smax[1]), fmaxf(smax[2], smax[3]));
        hx[blockIdx.x] = __float_as_uint(m);
    }
}

// ===========================================================================
// K2: wave-per-row stats. 4 rows/block. Wave 0 reduces hx once -> LDS
// broadcast. Butterfly-only row reductions (no per-row barriers). Packs
// xq8, stores mu/inv per row, plain-stores one hy[bid] per block.
// ===========================================================================
__global__ __launch_bounds__(256, 4) void rowstat_wave(
    const float* __restrict__ x, const float* __restrict__ gamma,
    const float* __restrict__ beta, const unsigned* __restrict__ hx,
    unsigned* __restrict__ hy,
    float* __restrict__ row_mu, float* __restrict__ row_inv,
    uint32_t* __restrict__ xq8) {
#pragma clang fp contract(off)
    const int bid = blockIdx.x;
    const int t = threadIdx.x;
    const int lane = t & 63;
    const int wave = t >> 6;
    const float4* g4 = (const float4*)gamma;
    const float4* b4 = (const float4*)beta;

    __shared__ float sS;
    __shared__ float redf[4];

    if (wave == 0) {
        unsigned mb = slots_max_u(hx, ABS_GRID, lane);
        if (lane == 0) sS = fmaxf(__uint_as_float(mb) / 127.0f, 1e-8f);
    }
    __syncthreads();
    const float s  = sS;
    const float rs = 1.0f / s;

    const int row = bid * 4 + wave;
    const float4* xr = (const float4*)(x + (size_t)row * NFEAT);

    uint32_t pk[16];
    int s1 = 0, s2 = 0;
#pragma unroll 4
    for (int c = 0; c < 16; ++c) {
        float4 v = xr[c * 64 + lane];
        float q0 = rintf(div_rn(v.x, s, rs));
        float q1 = rintf(div_rn(v.y, s, rs));
        float q2 = rintf(div_rn(v.z, s, rs));
        float q3 = rintf(div_rn(v.w, s, rs));
        q0 = fminf(fmaxf(q0, -127.0f), 127.0f);
        q1 = fminf(fmaxf(q1, -127.0f), 127.0f);
        q2 = fminf(fmaxf(q2, -127.0f), 127.0f);
        q3 = fminf(fmaxf(q3, -127.0f), 127.0f);
        int i0 = (int)q0, i1 = (int)q1, i2 = (int)q2, i3 = (int)q3;
        pk[c] = (uint32_t)(i0 & 255) | ((uint32_t)(i1 & 255) << 8) |
                ((uint32_t)(i2 & 255) << 16) | ((uint32_t)i3 << 24);
        s1 += i0 + i1 + i2 + i3;
        s2 += i0 * i0 + i1 * i1 + i2 * i2 + i3 * i3;
    }
#pragma unroll
    for (int off = 32; off; off >>= 1) {
        s1 += __shfl_xor(s1, off);
        s2 += __shfl_xor(s2, off);
    }
    // every lane computes mu/inv redundantly (identical bits; no serial sect.)
    float Ex  = (float)s1 * s;
    float Ex2 = (float)s2 * s * s;
    float mu  = Ex / (float)NFEAT;
    float var = fmaxf(Ex2 / (float)NFEAT - mu * mu, 0.0f);
    float vr  = fminf(fmaxf(rintf(var), 1.0f), 65535.0f);
    int sdi   = sqrt_rounded_ref((int)vr);
    float inv = 1.0f / fmaxf((float)sdi, 1e-5f);
    if (lane == 0) {
        row_mu[row]  = mu;
        row_inv[row] = inv;
    }

    uint32_t* xw = xq8 + (size_t)row * (NFEAT / 4);
#pragma unroll 4
    for (int c = 0; c < 16; ++c) xw[c * 64 + lane] = pk[c];

    float ym = 0.0f;
#pragma unroll 4
    for (int c = 0; c < 16; ++c) {
        uint32_t p = pk[c];
        float4 gm = g4[c * 64 + lane];
        float4 bt = b4[c * 64 + lane];
        int i0 = (int)(int8_t)(p & 255);
        int i1 = (int)(int8_t)((p >> 8) & 255);
        int i2 = (int)(int8_t)((p >> 16) & 255);
        int i3 = (int)(int8_t)((p >> 24) & 255);
        float y0 = ((float)i0 * s - mu) * inv * gm.x + bt.x;
        float y1 = ((float)i1 * s - mu) * inv * gm.y + bt.y;
        float y2 = ((float)i2 * s - mu) * inv * gm.z + bt.z;
        float y3 = ((float)i3 * s - mu) * inv * gm.w + bt.w;
        ym = fmaxf(ym, fmaxf(fmaxf(fabsf(y0), fabsf(y1)),
                             fmaxf(fabsf(y2), fabsf(y3))));
    }
#pragma unroll
    for (int off = 32; off; off >>= 1) ym = fmaxf(ym, __shfl_down(ym, off));
    if (lane == 0) redf[wave] = ym;
    __syncthreads();
    if (t == 0) {
        hy[bid] = __float_as_uint(fmaxf(fmaxf(redf[0], redf[1]),
                                        fmaxf(redf[2], redf[3])));
    }
}

// ===========================================================================
// K3: block-per-row output. Wave 0 reduces hx+hy once -> LDS broadcast.
// Reads xq8 (33 MB) + per-row stats; writes fp32 out. Bit-identical to K2's
// y values, then requantize with scale_out.
// ===========================================================================
__global__ __launch_bounds__(256, 4) void quantout_q2(
    const uint32_t* __restrict__ xq8, const float* __restrict__ gamma,
    const float* __restrict__ beta, const unsigned* __restrict__ hx,
    const unsigned* __restrict__ hy, int n_hy,
    const float* __restrict__ row_mu, const float* __restrict__ row_inv,
    float* __restrict__ out) {
#pragma clang fp contract(off)
    const int row = blockIdx.x;
    const int t = threadIdx.x;
    const int lane = t & 63;
    const int wave = t >> 6;

    __shared__ float sIn, sOut;
    if (wave == 0) {
        unsigned a = slots_max_u(hx, ABS_GRID, lane);
        unsigned b = slots_max_u(hy, n_hy, lane);
        if (lane == 0) {
            sIn  = fmaxf(__uint_as_float(a) / 127.0f, 1e-8f);
            sOut = fmaxf(__uint_as_float(b) / 127.0f, 1e-8f);
        }
    }
    __syncthreads();
    const float s_in  = sIn;
    const float s_out = sOut;
    const float rso = 1.0f / s_out;
    const float mu = row_mu[row], inv = row_inv[row];

    const uint32_t* xr = xq8 + (size_t)row * (NFEAT / 4);
    uint32_t p0 = xr[t];
    uint32_t p1 = xr[256 + t];
    uint32_t p2 = xr[512 + t];
    uint32_t p3 = xr[768 + t];
    uint32_t pp[4] = {p0, p1, p2, p3};
    float4* outr = (float4*)(out + (size_t)row * NFEAT);
#pragma unroll
    for (int g = 0; g < 4; ++g) {
        uint32_t p = pp[g];
        float4 gm = ((const float4*)gamma)[g * 256 + t];
        float4 bt = ((const float4*)beta)[g * 256 + t];
        float gv[4] = {gm.x, gm.y, gm.z, gm.w};
        float bv[4] = {bt.x, bt.y, bt.z, bt.w};
        int xs[4] = {(int)(int8_t)(p & 255), (int)(int8_t)((p >> 8) & 255),
                     (int)(int8_t)((p >> 16) & 255), (int)(int8_t)((p >> 24) & 255)};
        float o[4];
#pragma unroll
        for (int j = 0; j < 4; ++j) {
            float xq = (float)xs[j] * s_in;
            float xn = (xq - mu) * inv;
            float y = xn * gv[j] + bv[j];
            float q = rintf(div_rn(y, s_out, rso));
            q = fminf(fmaxf(q, -127.0f), 127.0f);
            o[j] = q * s_out;
        }
        outr[g * 256 + t] = make_float4(o[0], o[1], o[2], o[3]);
    }
}

// ===========================================================================
// Fallback (rows not divisible by 4 or ws too small): block-per-row variant
// reusing the same plain-store slot scheme with per-row hy slots.
// ===========================================================================
__global__ __launch_bounds__(256, 4) void rowstat_blk(
    const float* __restrict__ x, const float* __restrict__ gamma,
    const float* __restrict__ beta, const unsigned* __restrict__ hx,
    unsigned* __restrict__ hy,
    float* __restrict__ row_mu, float* __restrict__ row_inv) {
#pragma clang fp contract(off)
    const int row = blockIdx.x;
    const int t = threadIdx.x;
    const int lane = t & 63, w = t >> 6;
    __shared__ float sS;
    if (w == 0) {
        unsigned mb = slots_max_u(hx, ABS_GRID, lane);
        if (lane == 0) sS = fmaxf(__uint_as_float(mb) / 127.0f, 1e-8f);
    }
    __syncthreads();
    const float s = sS;
    const float rs = 1.0f / s;
    const float4* xr = (const float4*)(x + (size_t)row * NFEAT);
    float4 v0 = xr[t];
    float4 v1 = xr[256 + t];
    float4 v2 = xr[512 + t];
    float4 v3 = xr[768 + t];
    float xv[16] = {v0.x, v0.y, v0.z, v0.w, v1.x, v1.y, v1.z, v1.w,
                    v2.x, v2.y, v2.z, v2.w, v3.x, v3.y, v3.z, v3.w};
    int xi[16];
    int s1 = 0, s2 = 0;
#pragma unroll
    for (int k = 0; k < 16; ++k) {
        float q = rintf(div_rn(xv[k], s, rs));
        q = fminf(fmaxf(q, -127.0f), 127.0f);
        int qi = (int)q;
        xi[k] = qi;
        s1 += qi;
        s2 += qi * qi;
    }
#pragma unroll
    for (int off = 32; off; off >>= 1) {
        s1 += __shfl_down(s1, off);
        s2 += __shfl_down(s2, off);
    }
    __shared__ int a1[4], a2[4];
    __shared__ float smu1, sinv1;
    if (lane == 0) { a1[w] = s1; a2[w] = s2; }
    __syncthreads();
    if (t == 0) {
        int Exi = a1[0] + a1[1] + a1[2] + a1[3];
        int Ex2i = a2[0] + a2[1] + a2[2] + a2[3];
        float Ex = (float)Exi * s;
        float Ex2 = (float)Ex2i * s * s;
        float mu = Ex / (float)NFEAT;
        float var = fmaxf(Ex2 / (float)NFEAT - mu * mu, 0.0f);
        float vr = fminf(fmaxf(rintf(var), 1.0f), 65535.0f);
        int std_int = sqrt_rounded_ref((int)vr);
        float inv_std = 1.0f / fmaxf((float)std_int, 1e-5f);
        row_mu[row] = mu;
        row_inv[row] = inv_std;
        smu1 = mu;
        sinv1 = inv_std;
    }
    __syncthreads();
    const float mu = smu1, inv = sinv1;
    float ym = 0.0f;
#pragma unroll
    for (int g = 0; g < 4; ++g) {
        float4 gm = ((const float4*)gamma)[g * 256 + t];
        float4 bt = ((const float4*)beta)[g * 256 + t];
        float gv[4] = {gm.x, gm.y, gm.z, gm.w};
        float bv[4] = {bt.x, bt.y, bt.z, bt.w};
#pragma unroll
        for (int j = 0; j < 4; ++j) {
            float xq = (float)xi[g * 4 + j] * s;
            float xn = (xq - mu) * inv;
            float y = xn * gv[j] + bv[j];
            ym = fmaxf(ym, fabsf(y));
        }
    }
#pragma unroll
    for (int off = 32; off; off >>= 1) ym = fmaxf(ym, __shfl_down(ym, off));
    __shared__ float aym[4];
    if (lane == 0) aym[w] = ym;
    __syncthreads();
    if (t == 0)
        hy[row] = __float_as_uint(fmaxf(fmaxf(aym[0], aym[1]),
                                        fmaxf(aym[2], aym[3])));
}

__global__ __launch_bounds__(256, 4) void quantout_f2(
    const float* __restrict__ x, const float* __restrict__ gamma,
    const float* __restrict__ beta, const unsigned* __restrict__ hx,
    const unsigned* __restrict__ hy, int n_hy,
    const float* __restrict__ row_mu, const float* __restrict__ row_inv,
    float* __restrict__ out) {
#pragma clang fp contract(off)
    const int row = blockIdx.x;
    const int t = threadIdx.x;
    const int lane = t & 63, w = t >> 6;
    __shared__ float sIn, sOut;
    if (w == 0) {
        unsigned a = slots_max_u(hx, ABS_GRID, lane);
        unsigned b = slots_max_u(hy, n_hy, lane);
        if (lane == 0) {
            sIn  = fmaxf(__uint_as_float(a) / 127.0f, 1e-8f);
            sOut = fmaxf(__uint_as_float(b) / 127.0f, 1e-8f);
        }
    }
    __syncthreads();
    const float s_in = sIn, s_out = sOut;
    const float rsi = 1.0f / s_in;
    const float rso = 1.0f / s_out;
    const float mu = row_mu[row], inv = row_inv[row];
    const float4* xr = (const float4*)(x + (size_t)row * NFEAT);
    float4* outr = (float4*)(out + (size_t)row * NFEAT);
#pragma unroll
    for (int g = 0; g < 4; ++g) {
        float4 v = xr[g * 256 + t];
        float4 gm = ((const float4*)gamma)[g * 256 + t];
        float4 bt = ((const float4*)beta)[g * 256 + t];
        float xv[4] = {v.x, v.y, v.z, v.w};
        float gv[4] = {gm.x, gm.y, gm.z, gm.w};
        float bv[4] = {bt.x, bt.y, bt.z, bt.w};
        float o[4];
#pragma unroll
        for (int j = 0; j < 4; ++j) {
            float q = rintf(div_rn(xv[j], s_in, rsi));
            q = fminf(fmaxf(q, -127.0f), 127.0f);
            float xq = q * s_in;
            float xn = (xq - mu) * inv;
            float y = xn * gv[j] + bv[j];
            float qq = rintf(div_rn(y, s_out, rso));
            qq = fminf(fmaxf(qq, -127.0f), 127.0f);
            o[j] = qq * s_out;
        }
        outr[g * 256 + t] = make_float4(o[0], o[1], o[2], o[3]);
    }
}

extern "C" void kernel_launch(void* const* d_in, const int* in_sizes, int n_in,
                              void* d_out, int out_size, void* d_ws, size_t ws_size,
                              hipStream_t stream) {
    const float* x = (const float*)d_in[0];
    const float* gamma = (const float*)d_in[1];
    const float* beta = (const float*)d_in[2];
    float* out = (float*)d_out;

    const int total = in_sizes[0];
    const int rows = total / NFEAT;

    char* ws = (char*)d_ws;
    // layout: hx [0, 8192) ; hy [8192, 8192+rows*4) ; row_mu @64K ; row_inv ;
    // xq8 aligned after. All slots are fully written before any read -> no memset.
    unsigned* hx = (unsigned*)ws;
    unsigned* hy = (unsigned*)(ws + 8192);
    float* row_mu = (float*)(ws + 65536);
    float* row_inv = row_mu + rows;
    size_t xq_off = (65536 + (size_t)rows * 8 + 255) & ~(size_t)255;
    uint32_t* xq8 = (uint32_t*)(ws + xq_off);
    const bool fast = (rows % 4 == 0) && rows >= 4 &&
                      ws_size >= xq_off + (size_t)total + 256 &&
                      (size_t)rows * 4 + 8192 <= 65536;

    absmax_ps<<<ABS_GRID, 256, 0, stream>>>(x, total / 4, hx);

    if (fast) {
        rowstat_wave<<<rows / 4, 256, 0, stream>>>(x, gamma, beta, hx, hy,
                                                   row_mu, row_inv, xq8);
        quantout_q2<<<rows, 256, 0, stream>>>(xq8, gamma, beta, hx, hy,
                                              rows / 4, row_mu, row_inv, out);
    } else {
        rowstat_blk<<<rows, 256, 0, stream>>>(x, gamma, beta, hx, hy,
                                              row_mu, row_inv);
        quantout_f2<<<rows, 256, 0, stream>>>(x, gamma, beta, hx, hy,
                                              rows, row_mu, row_inv, out);
    }
}